// Round 2
// 270.797 us; speedup vs baseline: 1.1018x; 1.1018x over previous
//
#include <hip/hip_runtime.h>

// Problem constants
#define L_SEQ   4096
#define BSZQ    8
#define ROWS    (BSZQ * L_SEQ)      // 32768
#define KC1     512                 // GEMM1 K  (= H)
#define NC1     1024                // GEMM1 out cols (= 2*N interleaved re/im)
#define KC2     1024                // GEMM2 K
#define NC2     512                 // GEMM2 out cols (= H)
#define CHUNK   64
#define NCHUNK  64                  // L_SEQ / CHUNK

typedef __attribute__((ext_vector_type(8))) short bfrag;   // 8 bf16 (4 VGPRs)
typedef __attribute__((ext_vector_type(4))) float ffrag;   // 4 fp32 acc

static __device__ __forceinline__ unsigned short f2bf(float f) {
    union { float f; unsigned int u; } v; v.f = f;
    unsigned int r = v.u + 0x7fffu + ((v.u >> 16) & 1u);   // round-nearest-even
    return (unsigned short)(r >> 16);
}
static __device__ __forceinline__ unsigned int pk2(float a, float b) {
    return (unsigned int)f2bf(a) | ((unsigned int)f2bf(b) << 16);
}
static __device__ __forceinline__ float2 unpk2(unsigned int u) {
    union { unsigned int u; float f; } a, b;
    a.u = u << 16;
    b.u = u & 0xffff0000u;
    return make_float2(a.f, b.f);
}

// async global->LDS, 16B per lane; lds dest = wave-uniform base + lane*16
static __device__ __forceinline__ void async16(const void* g, void* l) {
    __builtin_amdgcn_global_load_lds(
        (const __attribute__((address_space(1))) unsigned int*)g,
        (__attribute__((address_space(3))) unsigned int*)l,
        16, 0, 0);
}

// ---------------- lam = exp(-exp(nu_log) + i*exp(theta_log)) ----------------
__global__ __launch_bounds__(512) void lru_lam_kernel(
    const float* __restrict__ nu_log, const float* __restrict__ theta_log,
    float2* __restrict__ lam)
{
    int n = threadIdx.x;
    float mag = expf(-expf(nu_log[n]));
    float th  = expf(theta_log[n]);
    lam[n] = make_float2(mag * cosf(th), mag * sinf(th));
}

// ------------- u (fp32) -> ub (bf16) with length mask folded in -------------
__global__ __launch_bounds__(256) void conv_mask_kernel(
    const float* __restrict__ u, const int* __restrict__ lengths,
    unsigned short* __restrict__ ub)
{
    int idx = blockIdx.x * 256 + threadIdx.x;   // 2,097,152 total (x8 elems)
    int row = idx >> 6;                         // flat row (b*L + l)
    int l = row & (L_SEQ - 1), b = row >> 12;
    bool keep = (l < lengths[b]);
    union { unsigned int s[4]; float4 f; } o;
    if (keep) {
        const float4 a = *(const float4*)(u + (size_t)idx * 8);
        const float4 c = *(const float4*)(u + (size_t)idx * 8 + 4);
        o.s[0] = pk2(a.x, a.y); o.s[1] = pk2(a.z, a.w);
        o.s[2] = pk2(c.x, c.y); o.s[3] = pk2(c.z, c.w);
    } else {
        o.s[0] = o.s[1] = o.s[2] = o.s[3] = 0u;
    }
    *(float4*)(ub + (size_t)idx * 8) = o.f;
}

// ---------------- Bt[n2][h] = bf16(B[h][n2])  (1024 x 512) ------------------
__global__ __launch_bounds__(256) void prep_Bt_kernel(
    const float* __restrict__ B, unsigned short* __restrict__ Bt)
{
    int idx = blockIdx.x * 256 + threadIdx.x;   // 524288 total
    int n2 = idx >> 9, h = idx & 511;
    Bt[idx] = f2bf(B[(size_t)h * 1024 + n2]);
}

// ---------------- Dt[j][2n+c] = bf16((c?-1:1) * C[c][n][j])  (512 x 1024) ---
__global__ __launch_bounds__(256) void prep_Dt_kernel(
    const float* __restrict__ C, unsigned short* __restrict__ Dt)
{
    int idx = blockIdx.x * 256 + threadIdx.x;   // 524288 total
    int j = idx >> 10, k = idx & 1023;
    int n = k >> 1, c = k & 1;
    float v = C[((size_t)c * 512 + n) * 512 + j];
    Dt[idx] = f2bf(c ? -v : v);
}

// ===================== 256x256 BK=64 8-wave 8-phase GEMM =====================
// Co[r,j] = sum_k A[r,k] * Bt[j,k].  8 waves (2 wm x 4 wn), per-wave 128x64.
// LDS: 2 x (A 32KB + B 32KB) = 128KB double buffer. XOR swizzle: within each
// 128B row, 16B chunk c -> c ^ (row&7); applied on the global SOURCE address
// at stage time (LDS dest linear, required by global_load_lds) and on the
// ds_read address (both-sides-or-neither).
// Phase schedule per iteration (2 K-tiles of 64; kt = 128*i):
//   P0 buf0(mh0,k0)  stage buf1.A0(kt+64)      reads: A4+B4
//   P1 buf0(mh0,k1)  stage buf1.A1(kt+64)      reads: A4+B4
//   P2 buf0(mh1,k0)  stage buf0.B0(kt+128)*    reads: A4
//   P3 buf0(mh1,k1)  stage buf0.B1(kt+128)*  vmcnt(4)*  reads: A4
//   P4 buf1(mh0,k0)  stage buf0.A0(kt+128)*    reads: A4+B4
//   P5 buf1(mh0,k1)  stage buf0.A1(kt+128)*    reads: A4+B4
//   P6 buf1(mh1,k0)  stage buf1.B0(kt+192)*    reads: A4
//   P7 buf1(mh1,k1)  stage buf1.B1(kt+192)*  vmcnt(4)*  reads: A4
// (* = only when a next iteration exists; last iteration P3 uses vmcnt(0))
// Ledger: at P3, outstanding = {prevP6,prevP7,P0,P1,P2,P3}=12 -> vmcnt(4)
// lands prev buf1.B + this buf1.A (needed at P4). At P7, outstanding =
// {P2..P7}=12 -> vmcnt(4) lands all of next buf0 (needed at next P0).
// WAR safety: each half's last ds_read drains (lgkmcnt(0)) before its phase's
// end barrier; restaging of that half is issued only after that barrier.
#define STAGE_HALF(GP, TB, HH, KT, GR0) do {                                   \
    _Pragma("unroll")                                                          \
    for (int j_ = 0; j_ < 2; j_++) {                                           \
        int c_ = j_ * 512 + tid;                                               \
        int r_ = (HH) * 128 + (c_ >> 3);                                       \
        int sw_ = (c_ & 7) ^ (r_ & 7);                                         \
        async16(GP + (size_t)((GR0) + r_) * KD + (KT) + sw_ * 8,               \
                &TB[(size_t)((HH) * 1024 + j_ * 512 + w * 64) * 8]);           \
    }                                                                          \
} while (0)

#define RD_A(H, MH, KK) do {                                                   \
    _Pragma("unroll")                                                          \
    for (int ri_ = 0; ri_ < 4; ri_++) {                                        \
        int r_ = wm * 128 + (MH) * 64 + ri_ * 16 + m16;                        \
        int cc_ = (KK) * 4 + q;                                                \
        af[ri_] = *(const bfrag*)&As[H][(size_t)(r_ * 8 + (cc_ ^ (r_ & 7))) * 8]; \
    }                                                                          \
} while (0)

#define RD_B(H, KK, DST) do {                                                  \
    _Pragma("unroll")                                                          \
    for (int ci_ = 0; ci_ < 4; ci_++) {                                        \
        int r_ = wn * 64 + ci_ * 16 + m16;                                     \
        int cc_ = (KK) * 4 + q;                                                \
        DST[ci_] = *(const bfrag*)&Bs[H][(size_t)(r_ * 8 + (cc_ ^ (r_ & 7))) * 8]; \
    }                                                                          \
} while (0)

#define MMQ(MH, BKR) do {                                                      \
    __builtin_amdgcn_s_setprio(1);                                             \
    _Pragma("unroll")                                                          \
    for (int ri_ = 0; ri_ < 4; ri_++)                                          \
    _Pragma("unroll")                                                          \
    for (int ci_ = 0; ci_ < 4; ci_++)                                          \
        acc[(MH) * 4 + ri_][ci_] = __builtin_amdgcn_mfma_f32_16x16x32_bf16(    \
            af[ri_], BKR[ci_], acc[(MH) * 4 + ri_][ci_], 0, 0, 0);             \
    __builtin_amdgcn_s_setprio(0);                                             \
} while (0)

#define BAR()   __builtin_amdgcn_s_barrier()
#define LGKM0() do { asm volatile("s_waitcnt lgkmcnt(0)" ::: "memory");        \
                     __builtin_amdgcn_sched_barrier(0); } while (0)

template<int KD, int ND, bool BF16OUT>
__global__ __launch_bounds__(512, 2) void mfma_gemm_8p(
    const unsigned short* __restrict__ A,   // row-major [., KD] bf16
    const unsigned short* __restrict__ Bt,  // row-major [ND, KD] bf16
    void* __restrict__ Co)
{
    __shared__ __align__(16) unsigned short As[2][256 * 64];  // 2 x 32KB
    __shared__ __align__(16) unsigned short Bs[2][256 * 64];  // 2 x 32KB

    const int tid = threadIdx.x;
    const int w = tid >> 6, lane = tid & 63;
    const int q = lane >> 4, m16 = lane & 15;
    const int wm = w >> 2, wn = w & 3;
    const int row0 = blockIdx.x * 256;
    const int col0 = blockIdx.y * 256;

    ffrag acc[8][4];
#pragma unroll
    for (int i = 0; i < 8; i++)
#pragma unroll
        for (int j = 0; j < 4; j++) acc[i][j] = (ffrag)0.f;

    bfrag af[4], b0f[4], b1f[4];

    // ---- prologue: buf0 full (kt=0) + buf1.B (kt=64); buf1.A comes at P0/P1
    STAGE_HALF(A,  As[0], 0, 0,  row0);
    STAGE_HALF(A,  As[0], 1, 0,  row0);
    STAGE_HALF(Bt, Bs[0], 0, 0,  col0);
    STAGE_HALF(Bt, Bs[0], 1, 0,  col0);
    STAGE_HALF(Bt, Bs[1], 0, 64, col0);
    STAGE_HALF(Bt, Bs[1], 1, 64, col0);
    asm volatile("s_waitcnt vmcnt(4)" ::: "memory");  // buf0 landed
    BAR();

    constexpr int NT = KD / 128;
    for (int i = 0; i < NT; i++) {
        const int kt = i * 128;
        const bool nl = (i + 1 < NT);
        // P0
        RD_A(0, 0, 0); RD_B(0, 0, b0f);
        STAGE_HALF(A, As[1], 0, kt + 64, row0);
        BAR(); LGKM0(); MMQ(0, b0f); BAR();
        // P1
        RD_A(0, 0, 1); RD_B(0, 1, b1f);
        STAGE_HALF(A, As[1], 1, kt + 64, row0);
        BAR(); LGKM0(); MMQ(0, b1f); BAR();
        // P2
        RD_A(0, 1, 0);
        if (nl) STAGE_HALF(Bt, Bs[0], 0, kt + 128, col0);
        BAR(); LGKM0(); MMQ(1, b0f); BAR();
        // P3
        RD_A(0, 1, 1);
        if (nl) STAGE_HALF(Bt, Bs[0], 1, kt + 128, col0);
        BAR(); LGKM0(); MMQ(1, b1f);
        if (nl) asm volatile("s_waitcnt vmcnt(4)" ::: "memory");
        else    asm volatile("s_waitcnt vmcnt(0)" ::: "memory");
        BAR();
        // P4
        RD_A(1, 0, 0); RD_B(1, 0, b0f);
        if (nl) STAGE_HALF(A, As[0], 0, kt + 128, row0);
        BAR(); LGKM0(); MMQ(0, b0f); BAR();
        // P5
        RD_A(1, 0, 1); RD_B(1, 1, b1f);
        if (nl) STAGE_HALF(A, As[0], 1, kt + 128, row0);
        BAR(); LGKM0(); MMQ(0, b1f); BAR();
        // P6
        RD_A(1, 1, 0);
        if (nl) STAGE_HALF(Bt, Bs[1], 0, kt + 192, col0);
        BAR(); LGKM0(); MMQ(1, b0f); BAR();
        // P7
        RD_A(1, 1, 1);
        if (nl) STAGE_HALF(Bt, Bs[1], 1, kt + 192, col0);
        BAR(); LGKM0(); MMQ(1, b1f);
        if (nl) asm volatile("s_waitcnt vmcnt(4)" ::: "memory");
        BAR();
    }

    if (BF16OUT) {
        // In-register re/im pairing: within frag ci, lanes 2j/2j+1 hold real
        // cols ci*16+2j / +1. shfl_xor(1) exchanges the pair; even lane packs
        // its own col as re, odd lane packs its own col as im. Each lane
        // stores one dword; bijective over the wave's 32 complex columns.
        unsigned int* Cb = (unsigned int*)Co;
        const int colc0 = (col0 >> 1) + wn * 32;
#pragma unroll
        for (int ri8 = 0; ri8 < 8; ri8++)
#pragma unroll
            for (int cp = 0; cp < 2; cp++)
#pragma unroll
                for (int r4 = 0; r4 < 4; r4++) {
                    float a0 = acc[ri8][cp * 2][r4];
                    float a1 = acc[ri8][cp * 2 + 1][r4];
                    float b0 = __shfl_xor(a0, 1);
                    float b1 = __shfl_xor(a1, 1);
                    unsigned int uo = (m16 & 1) ? pk2(b1, a1) : pk2(a0, b0);
                    int row = row0 + wm * 128 + ri8 * 16 + q * 4 + r4;
                    int ccol = (cp * 2 + (m16 & 1)) * 8 + (m16 >> 1);
                    Cb[(size_t)row * (ND / 2) + colc0 + ccol] = uo;
                }
    } else {
        float* Cf = (float*)Co;
#pragma unroll
        for (int ri8 = 0; ri8 < 8; ri8++)
#pragma unroll
            for (int r4 = 0; r4 < 4; r4++) {
                int row = row0 + wm * 128 + ri8 * 16 + q * 4 + r4;
#pragma unroll
                for (int ci = 0; ci < 4; ci++) {
                    int col = col0 + wn * 64 + ci * 16 + m16;
                    Cf[(size_t)row * ND + col] = acc[ri8][ci][r4];
                }
            }
    }
}

// ------- scan phase 1: chunk-final states only (bu is packed bf16) ----------
__global__ __launch_bounds__(512) void scan_states_kernel(
    const unsigned int* __restrict__ bu, const float2* __restrict__ lam,
    float2* __restrict__ states)
{
    int n = threadIdx.x;
    int b = blockIdx.x >> 6;
    int c = blockIdx.x & 63;
    float2 lm = lam[n];
    float xr = 0.f, xi = 0.f;
    bool fwd = (n < 256);
    int l0 = fwd ? (c * CHUNK) : (c * CHUNK + CHUNK - 1);
    const unsigned int* p = bu + ((size_t)b * L_SEQ + l0) * 512 + n;
    ptrdiff_t step = fwd ? 512 : -512;
#pragma unroll 8
    for (int t = 0; t < CHUNK; t++) {
        float2 v = unpk2(*p);
        float nr = lm.x * xr - lm.y * xi + v.x;
        float ni = lm.x * xi + lm.y * xr + v.y;
        xr = nr; xi = ni;
        p += step;
    }
    states[((size_t)b * NCHUNK + c) * 512 + n] = make_float2(xr, xi);
}

// ---------------- scan phase 2: combine chunk states -> exclusive carries ---
// Group-of-8 state preload: 8 independent loads in flight per group instead of
// 64 serial HBM round-trips (this kernel has only 8 blocks -> latency-bound).
__global__ __launch_bounds__(512) void scan_combine_kernel(
    const float2* __restrict__ states, float2* __restrict__ carries,
    const float2* __restrict__ lam)
{
    int n = threadIdx.x;
    int b = blockIdx.x;
    float2 lm = lam[n];
    float ar = lm.x, ai = lm.y;          // lam^64 by 6 squarings
#pragma unroll
    for (int i = 0; i < 6; i++) {
        float nr = ar * ar - ai * ai;
        ai = 2.f * ar * ai;
        ar = nr;
    }
    float cr = 0.f, ci = 0.f;
    bool fwd = (n < 256);
    for (int g = 0; g < 8; g++) {
        float2 s[8];
#pragma unroll
        for (int k = 0; k < 8; k++) {
            int c = fwd ? (g * 8 + k) : (63 - (g * 8 + k));
            s[k] = states[((size_t)b * NCHUNK + c) * 512 + n];
        }
#pragma unroll
        for (int k = 0; k < 8; k++) {
            int c = fwd ? (g * 8 + k) : (63 - (g * 8 + k));
            carries[((size_t)b * NCHUNK + c) * 512 + n] = make_float2(cr, ci);
            float nr = ar * cr - ai * ci + s[k].x;
            float ni = ar * ci + ai * cr + s[k].y;
            cr = nr; ci = ni;
        }
    }
}

// -------- scan phase 3: re-scan seeded with carry + mask, in place ----------
__global__ __launch_bounds__(512) void scan_apply_kernel(
    unsigned int* __restrict__ bu, const float2* __restrict__ carries,
    const float2* __restrict__ lam, const int* __restrict__ lengths)
{
    int n = threadIdx.x;
    int b = blockIdx.x >> 6;
    int c = blockIdx.x & 63;
    int len = lengths[b];
    float2 lm = lam[n];
    float2 cy = carries[((size_t)b * NCHUNK + c) * 512 + n];
    bool fwd = (n < 256);
    int l0 = fwd ? (c * CHUNK) : (c * CHUNK + CHUNK - 1);
    int dl = fwd ? 1 : -1;
    unsigned int* p = bu + ((size_t)b * L_SEQ + l0) * 512 + n;
    ptrdiff_t step = fwd ? 512 : -512;
    float xr = cy.x, xi = cy.y;
    int l = l0;
#pragma unroll 8
    for (int t = 0; t < CHUNK; t++) {
        float2 v = unpk2(*p);
        float nr = lm.x * xr - lm.y * xi + v.x;
        float ni = lm.x * xi + lm.y * xr + v.y;
        xr = nr; xi = ni;
        *p = (l >= len) ? 0u : pk2(xr, xi);
        p += step; l += dl;
    }
}

// ---------------- launch ----------------------------------------------------
extern "C" void kernel_launch(void* const* d_in, const int* in_sizes, int n_in,
                              void* d_out, int out_size, void* d_ws, size_t ws_size,
                              hipStream_t stream)
{
    const float* u        = (const float*)d_in[0];   // (8,4096,512)
    const int*   lengths  = (const int*)  d_in[1];   // (8,)
    const float* nu_log   = (const float*)d_in[2];   // (512,)
    const float* theta_log= (const float*)d_in[3];   // (512,)
    const float* B        = (const float*)d_in[4];   // (512,512,2) == (512 x 1024)
    const float* C        = (const float*)d_in[5];   // (2,512,512)
    float* y = (float*)d_out;                        // (8,4096,512)

    char* wp = (char*)d_ws;
    float2* lam     = (float2*)wp;  wp += 4096;
    float2* states  = (float2*)wp;  wp += (size_t)BSZQ * NCHUNK * 512 * 8;  // 2 MB
    float2* carries = (float2*)wp;  wp += (size_t)BSZQ * NCHUNK * 512 * 8;  // 2 MB
    unsigned int* bu = (unsigned int*)wp; wp += (size_t)ROWS * 512 * 4;     // 64 MB packed bf16
    unsigned short* ub = (unsigned short*)wp; wp += (size_t)ROWS * 512 * 2; // 32 MB
    unsigned short* Bt = (unsigned short*)wp; wp += (size_t)NC1 * KC1 * 2;  // 1 MB
    unsigned short* Dt = (unsigned short*)wp; wp += (size_t)NC2 * KC2 * 2;  // 1 MB

    lru_lam_kernel<<<1, 512, 0, stream>>>(nu_log, theta_log, lam);
    conv_mask_kernel<<<8192, 256, 0, stream>>>(u, lengths, ub);
    prep_Bt_kernel<<<2048, 256, 0, stream>>>(B, Bt);
    prep_Dt_kernel<<<2048, 256, 0, stream>>>(C, Dt);

    // GEMM1: bu(packed bf16) = ub @ Bt^T  (mask folded into ub)
    {
        dim3 grid(ROWS / 256, NC1 / 256);   // (128, 4)
        mfma_gemm_8p<KC1, NC1, true><<<grid, 512, 0, stream>>>(ub, Bt, bu);
    }

    scan_states_kernel<<<BSZQ * NCHUNK, 512, 0, stream>>>(bu, lam, states);
    scan_combine_kernel<<<BSZQ, 512, 0, stream>>>(states, carries, lam);
    scan_apply_kernel<<<BSZQ * NCHUNK, 512, 0, stream>>>(bu, carries, lam, lengths);

    // GEMM2: y = bu(=x, packed bf16) @ Dt^T, fp32 out
    {
        dim3 grid(ROWS / 256, NC2 / 256);   // (128, 2)
        mfma_gemm_8p<KC2, NC2, false><<<grid, 512, 0, stream>>>(
            (const unsigned short*)bu, Dt, y);
    }
}